// Round 3
// baseline (2055.881 us; speedup 1.0000x reference)
//
#include <hip/hip_runtime.h>

#define LL 16384
#define HH 128
#define WW 128
#define CC 64
#define NH 8
#define EPSF 1e-7f

// ---------------- zero scratch (KV/KS accumulators) ----------------
__global__ void zero_kernel(float* __restrict__ p, int n) {
    int i = blockIdx.x * 256 + threadIdx.x;
    if (i < n) p[i] = 0.f;
}

// ---------------- Kernel A: qkv 1x1 conv + bias (+relu on q,k) ----------------
// grid (64 pixel-blocks, B, 3 sections), block 256
__global__ void qkv_kernel(const float* __restrict__ x, const float* __restrict__ w,
                           const float* __restrict__ bias,
                           float* __restrict__ q, float* __restrict__ k, float* __restrict__ v) {
    const int pix = blockIdx.x * 256 + threadIdx.x;
    const int b   = blockIdx.y;
    const int sec = blockIdx.z;

    float xr[64];
    const float* xb = x + (size_t)b * CC * LL + pix;
#pragma unroll
    for (int c = 0; c < 64; ++c) xr[c] = xb[(size_t)c * LL];

    float* dst = (sec == 0) ? q : (sec == 1) ? k : v;
    const bool do_relu = (sec < 2);

    for (int ol = 0; ol < 64; ++ol) {
        const int o = sec * 64 + ol;
        const float* wr = w + o * 64;           // wave-uniform -> scalar loads
        float a0 = 0.f, a1 = 0.f, a2 = 0.f, a3 = 0.f;
#pragma unroll
        for (int c = 0; c < 64; c += 4) {
            a0 += xr[c]     * wr[c];
            a1 += xr[c + 1] * wr[c + 1];
            a2 += xr[c + 2] * wr[c + 2];
            a3 += xr[c + 3] * wr[c + 3];
        }
        float acc = (a0 + a1) + (a2 + a3) + bias[o];
        if (do_relu) acc = fmaxf(acc, 0.f);
        dst[(size_t)(b * 64 + ol) * LL + pix] = acc;
    }
}

// ---------------- Kernel B: KV = K_unfold^T @ V and Ksum, per (b,h) ----------------
// grid (16 row-chunks, NH, B), block 256: thread -> (c = tid>>5, lane s = tid&31)
__global__ void kv_kernel(const float* __restrict__ k, const float* __restrict__ v,
                          float* __restrict__ KV, float* __restrict__ KS) {
    const int chunk = blockIdx.x;
    const int h = blockIdx.y;
    const int b = blockIdx.z;
    const int tid = threadIdx.x;
    const int c = tid >> 5;
    const int s = tid & 31;

    const float* kc = k + ((size_t)(b * 64) + 8 * h + c) * LL;
    const float* vb = v + ((size_t)(b * 64) + 8 * h) * LL;

    float kv[9][8] = {{0.f}};
    float ks[9] = {0.f};

    for (int r = 0; r < 8; ++r) {
        const int y = chunk * 8 + r;
        for (int g = 0; g < 4; ++g) {
            const int col = s + 32 * g;
            float vv[8];
#pragma unroll
            for (int cp = 0; cp < 8; ++cp) vv[cp] = vb[(size_t)cp * LL + y * WW + col];
            float k9[9];
#pragma unroll
            for (int dy = -1; dy <= 1; ++dy)
#pragma unroll
                for (int dx = -1; dx <= 1; ++dx) {
                    const int yy = y + dy, xx = col + dx;
                    const bool ok = (yy >= 0 && yy < HH && xx >= 0 && xx < WW);
                    k9[(dy + 1) * 3 + (dx + 1)] = ok ? kc[yy * WW + xx] : 0.f;
                }
#pragma unroll
            for (int p = 0; p < 9; ++p) {
                ks[p] += k9[p];
#pragma unroll
                for (int cp = 0; cp < 8; ++cp) kv[p][cp] += k9[p] * vv[cp];
            }
        }
    }

    // reduce across the 32 lanes that share c (masks <=16 stay inside the 32-group)
#pragma unroll
    for (int p = 0; p < 9; ++p) {
#pragma unroll
        for (int m = 16; m >= 1; m >>= 1) ks[p] += __shfl_xor(ks[p], m);
#pragma unroll
        for (int cp = 0; cp < 8; ++cp) {
#pragma unroll
            for (int m = 16; m >= 1; m >>= 1) kv[p][cp] += __shfl_xor(kv[p][cp], m);
        }
    }

    if (s == 0) {
        const int base = ((b * NH + h) * 8 + c) * 9;
#pragma unroll
        for (int p = 0; p < 9; ++p) {
            atomicAdd(&KS[base + p], ks[p]);
#pragma unroll
            for (int cp = 0; cp < 8; ++cp)
                atomicAdd(&KV[(base + p) * 8 + cp], kv[p][cp]);
        }
    }
}

// ---------------- Kernel C: out = (Q_unfold @ KV) / (Q_unfold @ Ksum + EPS) ----------------
// grid (128 rows, NH, B), block 128 (thread = column)
__global__ void attn_kernel(const float* __restrict__ q, const float* __restrict__ KV,
                            const float* __restrict__ KS, float* __restrict__ ao) {
    const int y = blockIdx.x;
    const int h = blockIdx.y;
    const int b = blockIdx.z;
    const int col = threadIdx.x;

    float out[8] = {0.f};
    float den = 0.f;
    const int kvbase = (b * NH + h) * 8;

    for (int c = 0; c < 8; ++c) {
        const float* qc = q + ((size_t)(b * 64) + 8 * h + c) * LL;
        float q9[9];
#pragma unroll
        for (int dy = -1; dy <= 1; ++dy)
#pragma unroll
            for (int dx = -1; dx <= 1; ++dx) {
                const int yy = y + dy, xx = col + dx;
                const bool ok = (yy >= 0 && yy < HH && xx >= 0 && xx < WW);
                q9[(dy + 1) * 3 + (dx + 1)] = ok ? qc[yy * WW + xx] : 0.f;
            }
        const float* kvr = KV + ((size_t)(kvbase + c) * 9) * 8;  // wave-uniform -> scalar loads
        const float* ksr = KS + (size_t)(kvbase + c) * 9;
#pragma unroll
        for (int p = 0; p < 9; ++p) {
            const float qv = q9[p];
            den += qv * ksr[p];
#pragma unroll
            for (int cp = 0; cp < 8; ++cp) out[cp] += qv * kvr[p * 8 + cp];
        }
    }
    const float inv = 1.f / (den + EPSF);
    const int pix = y * WW + col;
#pragma unroll
    for (int cp = 0; cp < 8; ++cp)
        ao[((size_t)(b * 64) + h * 8 + cp) * LL + pix] = out[cp] * inv;
}

// ---------------- Kernel D: 3x3 conv 64->64 + bias, LDS-staged ----------------
// grid (256, B): blockIdx.x = y*2 + colhalf. Block 256 = 64 cols x 4 waves.
// Each wave (quarter q) computes 16 c_out for its 64 columns.
#define CI_CHUNK 16
__global__ __launch_bounds__(256, 4) void conv_kernel(const float* __restrict__ ao,
                                                      const float* __restrict__ w,
                                                      const float* __restrict__ bias,
                                                      float* __restrict__ out) {
    const int bx = blockIdx.x;
    const int y = bx >> 1;
    const int colbase = (bx & 1) * 64;
    const int b = blockIdx.y;
    const int colx = threadIdx.x & 63;      // 0..63
    const int q    = threadIdx.x >> 6;      // 0..3, wave-uniform

    // 3 rows x (64+2 halo) cols per ci, padded stride 72
    __shared__ float lds[CI_CHUNK][3][72];

    float acc[16];
#pragma unroll
    for (int j = 0; j < 16; ++j) acc[j] = 0.f;

    const float* aob = ao + (size_t)b * 64 * LL;

    for (int cc = 0; cc < 64; cc += CI_CHUNK) {
        __syncthreads();   // previous chunk's reads complete before overwrite
        // stage CI_CHUNK x 3 rows: 48 (ci,ry) pairs, 4 pairs per iteration (one per wave)
#pragma unroll
        for (int it = 0; it < 12; ++it) {
            const int pair = it * 4 + q;          // 0..47
            const int ci   = pair / 3;
            const int ry   = pair - ci * 3;
            const int gy   = y + ry - 1;
            const bool yok = (gy >= 0 && gy < HH);
            const float* src = aob + (size_t)(cc + ci) * LL + gy * WW;
            // main 64 columns (always in x-range)
            lds[ci][ry][1 + colx] = yok ? src[colbase + colx] : 0.f;
            // halo columns
            if (colx == 0) {
                const int gx = colbase - 1;
                lds[ci][ry][0] = (yok && gx >= 0) ? src[gx] : 0.f;
            }
            if (colx == 63) {
                const int gx = colbase + 64;
                lds[ci][ry][65] = (yok && gx < WW) ? src[gx] : 0.f;
            }
        }
        __syncthreads();

#pragma unroll 4
        for (int ci = 0; ci < CI_CHUNK; ++ci) {
            float a[9];
#pragma unroll
            for (int ry = 0; ry < 3; ++ry)
#pragma unroll
                for (int dx = 0; dx < 3; ++dx)
                    a[ry * 3 + dx] = lds[ci][ry][colx + dx];
            const int cig = cc + ci;
#pragma unroll
            for (int j = 0; j < 16; ++j) {
                const float* wr = w + (((q * 16 + j) * 64 + cig) * 9);  // wave-uniform -> s_load
                float t0 = fmaf(a[0], wr[0], acc[j]);
                t0 = fmaf(a[1], wr[1], t0);
                t0 = fmaf(a[2], wr[2], t0);
                t0 = fmaf(a[3], wr[3], t0);
                t0 = fmaf(a[4], wr[4], t0);
                t0 = fmaf(a[5], wr[5], t0);
                t0 = fmaf(a[6], wr[6], t0);
                t0 = fmaf(a[7], wr[7], t0);
                acc[j] = fmaf(a[8], wr[8], t0);
            }
        }
    }

    const int pix = y * WW + colbase + colx;
#pragma unroll
    for (int j = 0; j < 16; ++j) {
        const int o = q * 16 + j;
        out[((size_t)b * 64 + o) * LL + pix] = acc[j] + bias[o];
    }
}

extern "C" void kernel_launch(void* const* d_in, const int* in_sizes, int n_in,
                              void* d_out, int out_size, void* d_ws, size_t ws_size,
                              hipStream_t stream) {
    const float* x      = (const float*)d_in[0];
    const float* qkv_w  = (const float*)d_in[1];
    const float* qkv_b  = (const float*)d_in[2];
    const float* proj_w = (const float*)d_in[3];
    const float* proj_b = (const float*)d_in[4];
    float* out = (float*)d_out;
    float* ws  = (float*)d_ws;

    const size_t n1 = (size_t)4 * 64 * LL;      // one B*C*L fp32 plane set
    float* qb  = ws;
    float* kb  = ws + n1;
    float* vb  = ws + 2 * n1;
    float* aob = ws + 3 * n1;
    float* KV  = ws + 4 * n1;                   // 4*8*8*9*8 = 18432 floats
    float* KS  = KV + 4 * 8 * 8 * 9 * 8;        // 4*8*8*9  = 2304 floats

    const int nzero = 4 * 8 * 8 * 9 * 8 + 4 * 8 * 8 * 9;
    zero_kernel<<<(nzero + 255) / 256, 256, 0, stream>>>(KV, nzero);

    qkv_kernel<<<dim3(64, 4, 3), 256, 0, stream>>>(x, qkv_w, qkv_b, qb, kb, vb);
    kv_kernel<<<dim3(16, NH, 4), 256, 0, stream>>>(kb, vb, KV, KS);
    attn_kernel<<<dim3(128, NH, 4), 128, 0, stream>>>(qb, KV, KS, aob);
    conv_kernel<<<dim3(256, 4), 256, 0, stream>>>(aob, proj_w, proj_b, out);
}

// Round 4
// 424.172 us; speedup vs baseline: 4.8468x; 4.8468x over previous
//
#include <hip/hip_runtime.h>

#define LL 16384
#define HH 128
#define WW 128
#define CC 64
#define NH 8
#define EPSF 1e-7f

// ---------------- zero scratch (KV/KS accumulators) ----------------
__global__ void zero_kernel(float* __restrict__ p, int n) {
    int i = blockIdx.x * 256 + threadIdx.x;
    if (i < n) p[i] = 0.f;
}

// ---------------- Kernel A: qkv 1x1 conv + bias (+relu on q,k) ----------------
// grid (64 pixel-blocks, B, 3 sections), block 256
__global__ void qkv_kernel(const float* __restrict__ x, const float* __restrict__ w,
                           const float* __restrict__ bias,
                           float* __restrict__ q, float* __restrict__ k, float* __restrict__ v) {
    const int pix = blockIdx.x * 256 + threadIdx.x;
    const int b   = blockIdx.y;
    const int sec = blockIdx.z;

    float xr[64];
    const float* xb = x + (size_t)b * CC * LL + pix;
#pragma unroll
    for (int c = 0; c < 64; ++c) xr[c] = xb[(size_t)c * LL];

    float* dst = (sec == 0) ? q : (sec == 1) ? k : v;
    const bool do_relu = (sec < 2);

    for (int ol = 0; ol < 64; ++ol) {
        const int o = sec * 64 + ol;
        const float* wr = w + o * 64;           // wave-uniform -> scalar loads
        float a0 = 0.f, a1 = 0.f, a2 = 0.f, a3 = 0.f;
#pragma unroll
        for (int c = 0; c < 64; c += 4) {
            a0 += xr[c]     * wr[c];
            a1 += xr[c + 1] * wr[c + 1];
            a2 += xr[c + 2] * wr[c + 2];
            a3 += xr[c + 3] * wr[c + 3];
        }
        float acc = (a0 + a1) + (a2 + a3) + bias[o];
        if (do_relu) acc = fmaxf(acc, 0.f);
        dst[(size_t)(b * 64 + ol) * LL + pix] = acc;
    }
}

// ---------------- Kernel B: KV = K_unfold^T @ V and Ksum, per (b,h) ----------------
// grid (16 row-chunks, NH, B), block 256: thread -> (c = tid>>5, lane s = tid&31)
__global__ void kv_kernel(const float* __restrict__ k, const float* __restrict__ v,
                          float* __restrict__ KV, float* __restrict__ KS) {
    const int chunk = blockIdx.x;
    const int h = blockIdx.y;
    const int b = blockIdx.z;
    const int tid = threadIdx.x;
    const int c = tid >> 5;
    const int s = tid & 31;

    const float* kc = k + ((size_t)(b * 64) + 8 * h + c) * LL;
    const float* vb = v + ((size_t)(b * 64) + 8 * h) * LL;

    float kv[9][8] = {{0.f}};
    float ks[9] = {0.f};

    for (int r = 0; r < 8; ++r) {
        const int y = chunk * 8 + r;
        for (int g = 0; g < 4; ++g) {
            const int col = s + 32 * g;
            float vv[8];
#pragma unroll
            for (int cp = 0; cp < 8; ++cp) vv[cp] = vb[(size_t)cp * LL + y * WW + col];
            float k9[9];
#pragma unroll
            for (int dy = -1; dy <= 1; ++dy)
#pragma unroll
                for (int dx = -1; dx <= 1; ++dx) {
                    const int yy = y + dy, xx = col + dx;
                    const bool ok = (yy >= 0 && yy < HH && xx >= 0 && xx < WW);
                    k9[(dy + 1) * 3 + (dx + 1)] = ok ? kc[yy * WW + xx] : 0.f;
                }
#pragma unroll
            for (int p = 0; p < 9; ++p) {
                ks[p] += k9[p];
#pragma unroll
                for (int cp = 0; cp < 8; ++cp) kv[p][cp] += k9[p] * vv[cp];
            }
        }
    }

    // reduce across the 32 lanes that share c (masks <=16 stay inside the 32-group)
#pragma unroll
    for (int p = 0; p < 9; ++p) {
#pragma unroll
        for (int m = 16; m >= 1; m >>= 1) ks[p] += __shfl_xor(ks[p], m);
#pragma unroll
        for (int cp = 0; cp < 8; ++cp) {
#pragma unroll
            for (int m = 16; m >= 1; m >>= 1) kv[p][cp] += __shfl_xor(kv[p][cp], m);
        }
    }

    if (s == 0) {
        const int base = ((b * NH + h) * 8 + c) * 9;
#pragma unroll
        for (int p = 0; p < 9; ++p) {
            atomicAdd(&KS[base + p], ks[p]);
#pragma unroll
            for (int cp = 0; cp < 8; ++cp)
                atomicAdd(&KV[(base + p) * 8 + cp], kv[p][cp]);
        }
    }
}

// ---------------- Kernel C: out = (Q_unfold @ KV) / (Q_unfold @ Ksum + EPS) ----------------
// grid (128 rows, NH, B), block 128 (thread = column)
__global__ void attn_kernel(const float* __restrict__ q, const float* __restrict__ KV,
                            const float* __restrict__ KS, float* __restrict__ ao) {
    const int y = blockIdx.x;
    const int h = blockIdx.y;
    const int b = blockIdx.z;
    const int col = threadIdx.x;

    float out[8] = {0.f};
    float den = 0.f;
    const int kvbase = (b * NH + h) * 8;

    for (int c = 0; c < 8; ++c) {
        const float* qc = q + ((size_t)(b * 64) + 8 * h + c) * LL;
        float q9[9];
#pragma unroll
        for (int dy = -1; dy <= 1; ++dy)
#pragma unroll
            for (int dx = -1; dx <= 1; ++dx) {
                const int yy = y + dy, xx = col + dx;
                const bool ok = (yy >= 0 && yy < HH && xx >= 0 && xx < WW);
                q9[(dy + 1) * 3 + (dx + 1)] = ok ? qc[yy * WW + xx] : 0.f;
            }
        const float* kvr = KV + ((size_t)(kvbase + c) * 9) * 8;  // wave-uniform -> scalar loads
        const float* ksr = KS + (size_t)(kvbase + c) * 9;
#pragma unroll
        for (int p = 0; p < 9; ++p) {
            const float qv = q9[p];
            den += qv * ksr[p];
#pragma unroll
            for (int cp = 0; cp < 8; ++cp) out[cp] += qv * kvr[p * 8 + cp];
        }
    }
    const float inv = 1.f / (den + EPSF);
    const int pix = y * WW + col;
#pragma unroll
    for (int cp = 0; cp < 8; ++cp)
        ao[((size_t)(b * 64) + h * 8 + cp) * LL + pix] = out[cp] * inv;
}

// ---------------- Kernel D: 3x3 conv 64->64 + bias ----------------
// grid (256, B): blockIdx.x = y*2 + colhalf. Block 256 = 64 cols x 4 waves.
// Wave wv computes couts 16*wv..16*wv+15 for its 64 columns (lane = col).
// Weights for each 8-ci chunk staged in LDS (padded to 12 for float4 reads);
// pixel loads are direct bounds-checked global loads (R1-proven path).
#define CI_CHUNK 8
__global__ void conv_kernel(const float* __restrict__ ao, const float* __restrict__ w,
                            const float* __restrict__ bias, float* __restrict__ out) {
    const int bx = blockIdx.x;
    const int y = bx >> 1;
    const int colbase = (bx & 1) * 64;
    const int b = blockIdx.y;
    const int lane = threadIdx.x & 63;
    const int wv   = threadIdx.x >> 6;   // wave index 0..3, wave-uniform
    const int col  = colbase + lane;

    __shared__ float wlds[CI_CHUNK][64][12];   // 24 KB

    float acc[16];
#pragma unroll
    for (int j = 0; j < 16; ++j) acc[j] = 0.f;

    const float* aob = ao + (size_t)b * 64 * LL;

    for (int cc = 0; cc < 64; cc += CI_CHUNK) {
        __syncthreads();   // protect previous chunk's reads
        // stage weights: 8 ci x 64 co x 9 = 4608 dwords, 18 per thread
        for (int t = threadIdx.x; t < CI_CHUNK * 64 * 9; t += 256) {
            const int ci = t / 576;           // 64*9
            const int r  = t - ci * 576;
            const int co = r / 9;
            const int p  = r - co * 9;
            wlds[ci][co][p] = w[((co * 64) + (cc + ci)) * 9 + p];
        }
        __syncthreads();

        for (int ci = 0; ci < CI_CHUNK; ++ci) {
            float a[9];
            const float* src = aob + (size_t)(cc + ci) * LL;
#pragma unroll
            for (int dy = 0; dy < 3; ++dy) {
                const int yy = y + dy - 1;
#pragma unroll
                for (int dx = 0; dx < 3; ++dx) {
                    const int xx = col + dx - 1;
                    const bool ok = (yy >= 0 && yy < HH && xx >= 0 && xx < WW);
                    a[dy * 3 + dx] = ok ? src[yy * WW + xx] : 0.f;
                }
            }
#pragma unroll
            for (int j = 0; j < 16; ++j) {
                const int co = wv * 16 + j;   // wave-uniform -> LDS broadcast reads
                const float4 w0 = *(const float4*)&wlds[ci][co][0];
                const float4 w1 = *(const float4*)&wlds[ci][co][4];
                const float  w8 = wlds[ci][co][8];
                float t0 = fmaf(a[0], w0.x, acc[j]);
                t0 = fmaf(a[1], w0.y, t0);
                t0 = fmaf(a[2], w0.z, t0);
                t0 = fmaf(a[3], w0.w, t0);
                t0 = fmaf(a[4], w1.x, t0);
                t0 = fmaf(a[5], w1.y, t0);
                t0 = fmaf(a[6], w1.z, t0);
                t0 = fmaf(a[7], w1.w, t0);
                acc[j] = fmaf(a[8], w8, t0);
            }
        }
    }

    const int pix = y * WW + col;
#pragma unroll
    for (int j = 0; j < 16; ++j) {
        const int o = wv * 16 + j;
        out[((size_t)b * 64 + o) * LL + pix] = acc[j] + bias[o];
    }
}

extern "C" void kernel_launch(void* const* d_in, const int* in_sizes, int n_in,
                              void* d_out, int out_size, void* d_ws, size_t ws_size,
                              hipStream_t stream) {
    const float* x      = (const float*)d_in[0];
    const float* qkv_w  = (const float*)d_in[1];
    const float* qkv_b  = (const float*)d_in[2];
    const float* proj_w = (const float*)d_in[3];
    const float* proj_b = (const float*)d_in[4];
    float* out = (float*)d_out;
    float* ws  = (float*)d_ws;

    const size_t n1 = (size_t)4 * 64 * LL;      // one B*C*L fp32 plane set
    float* qb  = ws;
    float* kb  = ws + n1;
    float* vb  = ws + 2 * n1;
    float* aob = ws + 3 * n1;
    float* KV  = ws + 4 * n1;                   // 4*8*8*9*8 = 18432 floats
    float* KS  = KV + 4 * 8 * 8 * 9 * 8;        // 4*8*8*9  = 2304 floats

    const int nzero = 4 * 8 * 8 * 9 * 8 + 4 * 8 * 8 * 9;
    zero_kernel<<<(nzero + 255) / 256, 256, 0, stream>>>(KV, nzero);

    qkv_kernel<<<dim3(64, 4, 3), 256, 0, stream>>>(x, qkv_w, qkv_b, qb, kb, vb);
    kv_kernel<<<dim3(16, NH, 4), 256, 0, stream>>>(kb, vb, KV, KS);
    attn_kernel<<<dim3(128, NH, 4), 128, 0, stream>>>(qb, KV, KS, aob);
    conv_kernel<<<dim3(256, 4), 256, 0, stream>>>(aob, proj_w, proj_b, out);
}

// Round 5
// 332.721 us; speedup vs baseline: 6.1790x; 1.2749x over previous
//
#include <hip/hip_runtime.h>

#define LL 16384
#define HH 128
#define WW 128
#define CC 64
#define NH 8
#define EPSF 1e-7f
#define KVCHUNKS 32

// ---------------- Kernel A: qkv 1x1 conv + bias (+relu on q,k) ----------------
// grid (64 pixel-blocks, B, 3 sections), block 256
__global__ void qkv_kernel(const float* __restrict__ x, const float* __restrict__ w,
                           const float* __restrict__ bias,
                           float* __restrict__ q, float* __restrict__ k, float* __restrict__ v) {
    const int pix = blockIdx.x * 256 + threadIdx.x;
    const int b   = blockIdx.y;
    const int sec = blockIdx.z;

    float xr[64];
    const float* xb = x + (size_t)b * CC * LL + pix;
#pragma unroll
    for (int c = 0; c < 64; ++c) xr[c] = xb[(size_t)c * LL];

    float* dst = (sec == 0) ? q : (sec == 1) ? k : v;
    const bool do_relu = (sec < 2);

    for (int ol = 0; ol < 64; ++ol) {
        const int o = sec * 64 + ol;
        const float* wr = w + o * 64;           // wave-uniform -> scalar loads
        float a0 = 0.f, a1 = 0.f, a2 = 0.f, a3 = 0.f;
#pragma unroll
        for (int c = 0; c < 64; c += 4) {
            a0 += xr[c]     * wr[c];
            a1 += xr[c + 1] * wr[c + 1];
            a2 += xr[c + 2] * wr[c + 2];
            a3 += xr[c + 3] * wr[c + 3];
        }
        float acc = (a0 + a1) + (a2 + a3) + bias[o];
        if (do_relu) acc = fmaxf(acc, 0.f);
        dst[(size_t)(b * 64 + ol) * LL + pix] = acc;
    }
}

// ---------------- Kernel B: KV/KS partials, per (b,h,chunk) ----------------
// grid (32 chunks of 4 rows, NH, B) = 1024 blocks, block 256.
// 32-lane group per k-channel c; lanes 0-15 accumulate cp 0-3, lanes 16-31 cp 4-7.
// 45 accumulators/thread -> no spill. Partials stored to KVp, reduced by kv_finalize.
__global__ void kv_kernel(const float* __restrict__ k, const float* __restrict__ v,
                          float* __restrict__ KVp) {
    const int chunk = blockIdx.x;
    const int h = blockIdx.y;
    const int b = blockIdx.z;
    const int tid = threadIdx.x;
    const int c  = tid >> 5;          // 0..7
    const int s  = tid & 31;
    const int half = s >> 4;          // 0/1 -> cp half
    const int sl   = s & 15;
    const int cpb  = half * 4;

    const float* kc = k + ((size_t)(b * 64) + 8 * h + c) * LL;
    const float* vb = v + ((size_t)(b * 64) + 8 * h + cpb) * LL;

    float kv4[9][4] = {{0.f}};
    float ks[9] = {0.f};

    for (int r = 0; r < 4; ++r) {
        const int y = chunk * 4 + r;
        for (int g = 0; g < 8; ++g) {
            const int col = g * 16 + sl;
            float vv[4];
#pragma unroll
            for (int cp = 0; cp < 4; ++cp) vv[cp] = vb[(size_t)cp * LL + y * WW + col];
            float k9[9];
#pragma unroll
            for (int dy = -1; dy <= 1; ++dy)
#pragma unroll
                for (int dx = -1; dx <= 1; ++dx) {
                    const int yy = y + dy, xx = col + dx;
                    const bool ok = (yy >= 0 && yy < HH && xx >= 0 && xx < WW);
                    k9[(dy + 1) * 3 + (dx + 1)] = ok ? kc[yy * WW + xx] : 0.f;
                }
#pragma unroll
            for (int p = 0; p < 9; ++p) {
                ks[p] += k9[p];
#pragma unroll
                for (int cp = 0; cp < 4; ++cp)
                    kv4[p][cp] = fmaf(k9[p], vv[cp], kv4[p][cp]);
            }
        }
    }

    // reduce within each 16-lane half (masks 8,4,2,1)
#pragma unroll
    for (int p = 0; p < 9; ++p) {
#pragma unroll
        for (int m = 8; m >= 1; m >>= 1) ks[p] += __shfl_xor(ks[p], m);
#pragma unroll
        for (int cp = 0; cp < 4; ++cp) {
#pragma unroll
            for (int m = 8; m >= 1; m >>= 1) kv4[p][cp] += __shfl_xor(kv4[p][cp], m);
        }
    }

    if (sl == 0) {
        float* dst = KVp + (((size_t)(b * NH + h) * KVCHUNKS) + chunk) * 648;
#pragma unroll
        for (int p = 0; p < 9; ++p) {
#pragma unroll
            for (int cp = 0; cp < 4; ++cp)
                dst[(c * 9 + p) * 8 + cpb + cp] = kv4[p][cp];
            if (half == 0) dst[576 + c * 9 + p] = ks[p];   // ks duplicated in half 1
        }
    }
}

// ---------------- Kernel B2: reduce 32 chunk-partials -> KV, KS ----------------
// grid 32 (one per (b,h)), block 256
__global__ void kv_finalize(const float* __restrict__ KVp,
                            float* __restrict__ KV, float* __restrict__ KS) {
    const int bh = blockIdx.x;
    const float* src = KVp + (size_t)bh * KVCHUNKS * 648;
    for (int idx = threadIdx.x; idx < 648; idx += 256) {
        float s0 = 0.f, s1 = 0.f, s2 = 0.f, s3 = 0.f;
#pragma unroll
        for (int ch = 0; ch < KVCHUNKS; ch += 4) {
            s0 += src[(ch + 0) * 648 + idx];
            s1 += src[(ch + 1) * 648 + idx];
            s2 += src[(ch + 2) * 648 + idx];
            s3 += src[(ch + 3) * 648 + idx];
        }
        const float sum = (s0 + s1) + (s2 + s3);
        if (idx < 576) KV[(size_t)bh * 576 + idx] = sum;
        else           KS[(size_t)bh * 72 + (idx - 576)] = sum;
    }
}

// ---------------- Kernel C: out = (Q_unfold @ KV) / (Q_unfold @ Ksum + EPS) ----------------
// grid (128 rows, NH, B), block 128 (thread = column)
__global__ void attn_kernel(const float* __restrict__ q, const float* __restrict__ KV,
                            const float* __restrict__ KS, float* __restrict__ ao) {
    const int y = blockIdx.x;
    const int h = blockIdx.y;
    const int b = blockIdx.z;
    const int col = threadIdx.x;

    float out[8] = {0.f};
    float den = 0.f;
    const int kvbase = (b * NH + h) * 8;

    for (int c = 0; c < 8; ++c) {
        const float* qc = q + ((size_t)(b * 64) + 8 * h + c) * LL;
        float q9[9];
#pragma unroll
        for (int dy = -1; dy <= 1; ++dy)
#pragma unroll
            for (int dx = -1; dx <= 1; ++dx) {
                const int yy = y + dy, xx = col + dx;
                const bool ok = (yy >= 0 && yy < HH && xx >= 0 && xx < WW);
                q9[(dy + 1) * 3 + (dx + 1)] = ok ? qc[yy * WW + xx] : 0.f;
            }
        const float* kvr = KV + ((size_t)(kvbase + c) * 9) * 8;  // wave-uniform -> scalar loads
        const float* ksr = KS + (size_t)(kvbase + c) * 9;
#pragma unroll
        for (int p = 0; p < 9; ++p) {
            const float qv = q9[p];
            den += qv * ksr[p];
#pragma unroll
            for (int cp = 0; cp < 8; ++cp) out[cp] += qv * kvr[p * 8 + cp];
        }
    }
    const float inv = 1.f / (den + EPSF);
    const int pix = y * WW + col;
#pragma unroll
    for (int cp = 0; cp < 8; ++cp)
        ao[((size_t)(b * 64) + h * 8 + cp) * LL + pix] = out[cp] * inv;
}

// ---------------- Kernel D: 3x3 conv 64->64 + bias ----------------
// grid (256, B): blockIdx.x = y*2 + colhalf. Block 256 = 64 cols x 4 waves.
// Wave wv computes couts 16*wv..16*wv+15 for its 64 columns (lane = col).
// Weights for each 8-ci chunk staged in LDS (padded to 12 for float4 reads).
#define CI_CHUNK 8
__global__ void conv_kernel(const float* __restrict__ ao, const float* __restrict__ w,
                            const float* __restrict__ bias, float* __restrict__ out) {
    const int bx = blockIdx.x;
    const int y = bx >> 1;
    const int colbase = (bx & 1) * 64;
    const int b = blockIdx.y;
    const int lane = threadIdx.x & 63;
    const int wv   = threadIdx.x >> 6;   // wave index 0..3, wave-uniform
    const int col  = colbase + lane;

    __shared__ float wlds[CI_CHUNK][64][12];   // 24 KB

    float acc[16];
#pragma unroll
    for (int j = 0; j < 16; ++j) acc[j] = 0.f;

    const float* aob = ao + (size_t)b * 64 * LL;

    for (int cc = 0; cc < 64; cc += CI_CHUNK) {
        __syncthreads();   // protect previous chunk's reads
        // stage weights: 8 ci x 64 co x 9 = 4608 dwords, 18 per thread
        for (int t = threadIdx.x; t < CI_CHUNK * 64 * 9; t += 256) {
            const int ci = t / 576;           // 64*9
            const int r  = t - ci * 576;
            const int co = r / 9;
            const int p  = r - co * 9;
            wlds[ci][co][p] = w[((co * 64) + (cc + ci)) * 9 + p];
        }
        __syncthreads();

        for (int ci = 0; ci < CI_CHUNK; ++ci) {
            float a[9];
            const float* src = aob + (size_t)(cc + ci) * LL;
#pragma unroll
            for (int dy = 0; dy < 3; ++dy) {
                const int yy = y + dy - 1;
#pragma unroll
                for (int dx = 0; dx < 3; ++dx) {
                    const int xx = col + dx - 1;
                    const bool ok = (yy >= 0 && yy < HH && xx >= 0 && xx < WW);
                    a[dy * 3 + dx] = ok ? src[yy * WW + xx] : 0.f;
                }
            }
#pragma unroll
            for (int j = 0; j < 16; ++j) {
                const int co = wv * 16 + j;   // wave-uniform -> LDS broadcast reads
                const float4 w0 = *(const float4*)&wlds[ci][co][0];
                const float4 w1 = *(const float4*)&wlds[ci][co][4];
                const float  w8 = wlds[ci][co][8];
                float t0 = fmaf(a[0], w0.x, acc[j]);
                t0 = fmaf(a[1], w0.y, t0);
                t0 = fmaf(a[2], w0.z, t0);
                t0 = fmaf(a[3], w0.w, t0);
                t0 = fmaf(a[4], w1.x, t0);
                t0 = fmaf(a[5], w1.y, t0);
                t0 = fmaf(a[6], w1.z, t0);
                t0 = fmaf(a[7], w1.w, t0);
                acc[j] = fmaf(a[8], w8, t0);
            }
        }
    }

    const int pix = y * WW + col;
#pragma unroll
    for (int j = 0; j < 16; ++j) {
        const int o = wv * 16 + j;
        out[((size_t)b * 64 + o) * LL + pix] = acc[j] + bias[o];
    }
}

extern "C" void kernel_launch(void* const* d_in, const int* in_sizes, int n_in,
                              void* d_out, int out_size, void* d_ws, size_t ws_size,
                              hipStream_t stream) {
    const float* x      = (const float*)d_in[0];
    const float* qkv_w  = (const float*)d_in[1];
    const float* qkv_b  = (const float*)d_in[2];
    const float* proj_w = (const float*)d_in[3];
    const float* proj_b = (const float*)d_in[4];
    float* out = (float*)d_out;
    float* ws  = (float*)d_ws;

    const size_t n1 = (size_t)4 * 64 * LL;      // one B*C*L fp32 plane set
    float* qb  = ws;
    float* kb  = ws + n1;
    float* vb  = ws + 2 * n1;
    float* aob = ws + 3 * n1;
    float* KV  = ws + 4 * n1;                   // 4*8*8*9*8 = 18432 floats
    float* KS  = KV + 4 * 8 * 8 * 9 * 8;        // 4*8*8*9  = 2304 floats
    float* KVp = KS + 4 * 8 * 8 * 9;            // 32*32*648 = 663552 floats

    qkv_kernel<<<dim3(64, 4, 3), 256, 0, stream>>>(x, qkv_w, qkv_b, qb, kb, vb);
    kv_kernel<<<dim3(KVCHUNKS, NH, 4), 256, 0, stream>>>(kb, vb, KVp);
    kv_finalize<<<32, 256, 0, stream>>>(KVp, KV, KS);
    attn_kernel<<<dim3(128, NH, 4), 128, 0, stream>>>(qb, KV, KS, aob);
    conv_kernel<<<dim3(256, 4), 256, 0, stream>>>(aob, proj_w, proj_b, out);
}